// Round 9
// baseline (281.746 us; speedup 1.0000x reference)
//
#include <hip/hip_runtime.h>
#include <hip/hip_bf16.h>

#define N_NODES 100000
#define N_EDGES 1600000
#define IN_F 128
#define OUT_F 64

#define RPB 64                        // rows per bucket
#define NB  1563                      // ceil(100000/64)
#define C_CHUNKS 250                  // edge chunks (scatter/hist blocks)
#define CHUNK 6400                    // edges per chunk; 250*6400 = 1,600,000
#define M_CNT (NB * C_CHUNKS)         // 390,750 bucket-major counters
#define SCANA_BLOCKS ((M_CNT + 1023) / 1024)   // 382

typedef __attribute__((ext_vector_type(8))) short short8;
typedef __attribute__((ext_vector_type(4))) float f32x4;

#define LDS_PITCH 136

__device__ __forceinline__ unsigned short f2bf(float x) {
    unsigned u = __float_as_uint(x);
    return (unsigned short)((u + 0x7FFFu + ((u >> 16) & 1u)) >> 16);  // RNE
}

// ---------------------------------------------------------------------------
// K1: per-chunk bucket histogram -> cnt[b*C_CHUNKS + c]; block C_CHUNKS
// additionally computes wa1 = W@a1, wa2 = W@a2 (fused k_wa, saves a launch).
// ---------------------------------------------------------------------------
__global__ __launch_bounds__(1024) void k_hist(
    const int* __restrict__ ei, int* __restrict__ cnt,
    const float* __restrict__ W, const float* __restrict__ a1,
    const float* __restrict__ a2, float* __restrict__ wa1, float* __restrict__ wa2)
{
    __shared__ int hl[NB];
    const int c = blockIdx.x;
    if (c == C_CHUNKS) {                 // fused k_wa
        const int k = threadIdx.x;
        if (k < IN_F) {
            float s1 = 0.f, s2 = 0.f;
            #pragma unroll 8
            for (int f = 0; f < OUT_F; f++) {
                const float w = W[k * OUT_F + f];
                s1 += w * a1[f];
                s2 += w * a2[f];
            }
            wa1[k] = s1;
            wa2[k] = s2;
        }
        return;
    }
    for (int i = threadIdx.x; i < NB; i += 1024) hl[i] = 0;
    __syncthreads();
    const int e0 = c * CHUNK;
    for (int i = threadIdx.x; i < CHUNK; i += 1024)
        atomicAdd(&hl[ei[e0 + i] >> 6], 1);
    __syncthreads();
    for (int b = threadIdx.x; b < NB; b += 1024)
        cnt[b * C_CHUNKS + c] = hl[b];
}

// ---------------------------------------------------------------------------
// K2: Wh = h @ W via bf16 MFMA; f1/f2 fused in fp32. Wh stored as bf16
// (only k_agg consumes it; softmax path stays fp32 via wa1/wa2).
// ---------------------------------------------------------------------------
__global__ __launch_bounds__(256) void k_gemm(
    const float* __restrict__ h, const float* __restrict__ W,
    const float* __restrict__ wa1, const float* __restrict__ wa2,
    unsigned short* __restrict__ Whb, float* __restrict__ f1, float* __restrict__ f2)
{
    __shared__ unsigned short Wt[OUT_F * LDS_PITCH];
    __shared__ unsigned short Al[16 * LDS_PITCH];

    const int tid  = threadIdx.x;
    const int lane = tid & 63;
    const int wav  = tid >> 6;
    const int quad = lane >> 4;
    const int nl   = lane & 15;

    for (int i = tid; i < IN_F * OUT_F; i += 256) {
        const int k = i >> 6, f = i & 63;
        Wt[f * LDS_PITCH + k] = f2bf(W[i]);
    }
    __syncthreads();

    short8 bfrag[4];
    #pragma unroll
    for (int ch = 0; ch < 4; ch++)
        bfrag[ch] = *(const short8*)&Wt[(wav * 16 + nl) * LDS_PITCH + ch * 32 + quad * 8];

    const int srow = tid >> 4;
    const int sc   = tid & 15;
    float w1r[8], w2r[8];
    #pragma unroll
    for (int j = 0; j < 8; j++) { w1r[j] = wa1[sc * 8 + j]; w2r[j] = wa2[sc * 8 + j]; }

    const int ntiles = N_NODES / 16;
    for (int tile = blockIdx.x; tile < ntiles; tile += gridDim.x) {
        const int base = tile * 16;
        __syncthreads();

        const float4 v0 = *(const float4*)&h[(base + srow) * IN_F + sc * 8];
        const float4 v1 = *(const float4*)&h[(base + srow) * IN_F + sc * 8 + 4];
        float p1 = v0.x * w1r[0] + v0.y * w1r[1] + v0.z * w1r[2] + v0.w * w1r[3]
                 + v1.x * w1r[4] + v1.y * w1r[5] + v1.z * w1r[6] + v1.w * w1r[7];
        float p2 = v0.x * w2r[0] + v0.y * w2r[1] + v0.z * w2r[2] + v0.w * w2r[3]
                 + v1.x * w2r[4] + v1.y * w2r[5] + v1.z * w2r[6] + v1.w * w2r[7];
        #pragma unroll
        for (int m = 8; m >= 1; m >>= 1) {
            p1 += __shfl_xor(p1, m, 64);
            p2 += __shfl_xor(p2, m, 64);
        }
        if (sc == 0) { f1[base + srow] = p1; f2[base + srow] = p2; }

        uint4 packed;
        packed.x = (unsigned)f2bf(v0.x) | ((unsigned)f2bf(v0.y) << 16);
        packed.y = (unsigned)f2bf(v0.z) | ((unsigned)f2bf(v0.w) << 16);
        packed.z = (unsigned)f2bf(v1.x) | ((unsigned)f2bf(v1.y) << 16);
        packed.w = (unsigned)f2bf(v1.z) | ((unsigned)f2bf(v1.w) << 16);
        *(uint4*)&Al[srow * LDS_PITCH + sc * 8] = packed;

        __syncthreads();

        f32x4 acc = {0.f, 0.f, 0.f, 0.f};
        #pragma unroll
        for (int ch = 0; ch < 4; ch++) {
            const short8 afrag = *(const short8*)&Al[nl * LDS_PITCH + ch * 32 + quad * 8];
            acc = __builtin_amdgcn_mfma_f32_16x16x32_bf16(afrag, bfrag[ch], acc, 0, 0, 0);
        }

        const int col = wav * 16 + nl;
        #pragma unroll
        for (int r = 0; r < 4; r++)
            Whb[(base + quad * 4 + r) * OUT_F + col] = f2bf(acc[r]);
    }
}

// ---------------------------------------------------------------------------
// K3a: per-1024-chunk totals of cnt
// ---------------------------------------------------------------------------
__global__ __launch_bounds__(256) void k_scanA(const int* __restrict__ cnt,
                                               int* __restrict__ bsum)
{
    __shared__ int sd[256];
    const int t = threadIdx.x;
    const int i0 = blockIdx.x * 1024 + t * 4;
    int s = 0;
    #pragma unroll
    for (int k = 0; k < 4; k++) {
        const int i = i0 + k;
        s += (i < M_CNT) ? cnt[i] : 0;
    }
    sd[t] = s; __syncthreads();
    for (int off = 128; off >= 1; off >>= 1) {
        if (t < off) sd[t] += sd[t + off];
        __syncthreads();
    }
    if (t == 0) bsum[blockIdx.x] = sd[0];
}

// ---------------------------------------------------------------------------
// K3b: in-place exclusive scan of cnt; each block reduces its own bsum
// prefix (<=382 ints) internally — replaces the old separate scanB launch.
// ---------------------------------------------------------------------------
__global__ __launch_bounds__(256) void k_scanC(int* __restrict__ cnt,
                                               const int* __restrict__ bsum)
{
    __shared__ int red[256];
    __shared__ int ts[256];
    const int t = threadIdx.x;

    int pv = 0;
    for (int i = t; i < (int)blockIdx.x; i += 256) pv += bsum[i];
    red[t] = pv; __syncthreads();
    for (int off = 128; off >= 1; off >>= 1) {
        if (t < off) red[t] += red[t + off];
        __syncthreads();
    }
    const int bpref = red[0];

    const int i0 = blockIdx.x * 1024 + t * 4;
    int v[4]; int s = 0;
    #pragma unroll
    for (int k = 0; k < 4; k++) {
        const int i = i0 + k;
        v[k] = (i < M_CNT) ? cnt[i] : 0;
        s += v[k];
    }
    ts[t] = s; __syncthreads();
    for (int off = 1; off < 256; off <<= 1) {
        const int x = (t >= off) ? ts[t - off] : 0;
        __syncthreads();
        ts[t] += x;
        __syncthreads();
    }
    int excl = ts[t] - s + bpref;
    #pragma unroll
    for (int k = 0; k < 4; k++) {
        const int i = i0 + k;
        if (i < M_CNT) cnt[i] = excl;
        excl += v[k];
    }
}

// ---------------------------------------------------------------------------
// K4: binned scatter (LDS cursors only). pair = {(rlocal<<17)|col, eexp}
// ---------------------------------------------------------------------------
__global__ __launch_bounds__(1024) void k_scatter(
    const int* __restrict__ ei,
    const float* __restrict__ f1,
    const float* __restrict__ f2,
    const int* __restrict__ cnt,
    uint2* __restrict__ pairs)
{
    __shared__ int cur[NB];
    const int c = blockIdx.x;
    for (int b = threadIdx.x; b < NB; b += 1024)
        cur[b] = cnt[b * C_CHUNKS + c];
    __syncthreads();

    const int e0 = c * CHUNK;
    for (int i = threadIdx.x; i < CHUNK; i += 1024) {
        const int r  = ei[e0 + i];
        const int cl = ei[N_EDGES + e0 + i];
        float x = f1[r] + f2[cl];
        x = (x >= 0.f) ? x : 0.2f * x;
        const float ee = __expf(x);
        const int pos = atomicAdd(&cur[r >> 6], 1);
        pairs[pos] = make_uint2(((unsigned)(r & 63) << 17) | (unsigned)cl,
                                __float_as_uint(ee));
    }
}

// ---------------------------------------------------------------------------
// K5: per-bucket streaming row-sort: pairs -> pairs2 (row-grouped) + rowptr
// ---------------------------------------------------------------------------
__global__ __launch_bounds__(256) void k_sort(
    const int* __restrict__ cnt,
    const uint2* __restrict__ pairs,
    uint2* __restrict__ pairs2,
    int* __restrict__ rowptr)
{
    __shared__ int cnt64[64];
    __shared__ int cur64[64];

    const int b   = blockIdx.x;
    const int tid = threadIdx.x;
    const int start = cnt[b * C_CHUNKS];
    const int end   = (b == NB - 1) ? N_EDGES : cnt[(b + 1) * C_CHUNKS];

    if (tid < 64) cnt64[tid] = 0;
    __syncthreads();

    for (int i = start + tid; i < end; i += 256)
        atomicAdd(&cnt64[pairs[i].x >> 17], 1);
    __syncthreads();

    if (tid < 64) {
        const int v = cnt64[tid];
        int s = v;
        #pragma unroll
        for (int off = 1; off < 64; off <<= 1) {
            const int x = __shfl_up(s, off, 64);
            if (tid >= off) s += x;
        }
        cur64[tid] = s - v;
        const int g = b * 64 + tid;
        if (g < N_NODES) rowptr[g] = start + s - v;
    }
    __syncthreads();

    for (int i = start + tid; i < end; i += 256) {
        const uint2 p = pairs[i];
        const int pos = atomicAdd(&cur64[p.x >> 17], 1);
        pairs2[start + pos] = p;
    }
    if (b == 0 && tid == 0) rowptr[N_NODES] = N_EDGES;
}

// ---------------------------------------------------------------------------
// K6: wave-per-node aggregation, masked 8-deep batches (full ILP incl. tail).
// Wh gathered as bf16 rows (128 B) — halves the random-gather line traffic.
// ---------------------------------------------------------------------------
__global__ __launch_bounds__(256) void k_agg(
    const int* __restrict__ rowptr,
    const uint2* __restrict__ pairs2,
    const unsigned short* __restrict__ Whb,
    float* __restrict__ out)
{
    const int wid  = (blockIdx.x * 256 + threadIdx.x) >> 6;
    const int lane = threadIdx.x & 63;
    if (wid >= N_NODES) return;

    const int start = rowptr[wid];
    const int end   = rowptr[wid + 1];

    float acc = 0.f, s = 0.f;
    for (int j = start; j < end; j += 8) {
        #pragma unroll
        for (int k = 0; k < 8; k++) {
            const int  jj = j + k;
            const bool v  = jj < end;
            const uint2 p = pairs2[v ? jj : start];
            const float ee = v ? __uint_as_float(p.y) : 0.f;
            const float wh = __uint_as_float(
                (unsigned)Whb[(((int)(p.x & 0x1FFFFu)) << 6) + lane] << 16);
            acc += ee * wh;
            s   += ee;
        }
    }

    const float r = acc / (s + 1e-10f);
    out[wid * OUT_F + lane] = (r > 0.f) ? r : expm1f(r);
}

extern "C" void kernel_launch(void* const* d_in, const int* in_sizes, int n_in,
                              void* d_out, int out_size, void* d_ws, size_t ws_size,
                              hipStream_t stream) {
    const float* h  = (const float*)d_in[0];
    const float* W  = (const float*)d_in[1];
    const float* a1 = (const float*)d_in[2];
    const float* a2 = (const float*)d_in[3];
    const int* ei   = (const int*)d_in[4];
    float* out      = (float*)d_out;

    float* ws = (float*)d_ws;
    unsigned short* Whb = (unsigned short*)ws;        // 6.4M ushort = 3.2M f
    float* f1     = ws + 3200000;                     // 100,000
    float* f2     = f1 + N_NODES;                     // 100,000
    float* wa1    = f2 + N_NODES;                     // 128
    float* wa2    = wa1 + 128;                        // 128
    int*   cnt    = (int*)(wa2 + 128);                // 390,750
    int*   bsum   = cnt + M_CNT;                      // 384
    int*   rowptr = bsum + 384;                       // 100,002
    int*   pad    = rowptr + 100002;
    if ((size_t)(pad - (int*)ws) & 1) pad++;          // 8B align
    uint2* pairs  = (uint2*)pad;                      // 1.6M x 8B
    uint2* pairs2 = pairs + N_EDGES;                  // 1.6M x 8B

    k_hist   <<<C_CHUNKS + 1, 1024, 0, stream>>>(ei, cnt, W, a1, a2, wa1, wa2);
    k_scanA  <<<SCANA_BLOCKS, 256, 0, stream>>>(cnt, bsum);
    k_scanC  <<<SCANA_BLOCKS, 256, 0, stream>>>(cnt, bsum);
    k_gemm   <<<1250, 256, 0, stream>>>(h, W, wa1, wa2, Whb, f1, f2);
    k_scatter<<<C_CHUNKS, 1024, 0, stream>>>(ei, f1, f2, cnt, pairs);
    k_sort   <<<NB, 256, 0, stream>>>(cnt, pairs, pairs2, rowptr);
    k_agg    <<<(N_NODES * 64 + 255) / 256, 256, 0, stream>>>(rowptr, pairs2, Whb, out);
}

// Round 10
// 229.691 us; speedup vs baseline: 1.2266x; 1.2266x over previous
//
#include <hip/hip_runtime.h>
#include <hip/hip_bf16.h>

#define N_NODES 100000
#define N_EDGES 1600000
#define IN_F 128
#define OUT_F 64

#define RPB 64                        // rows per bucket
#define NB  1563                      // ceil(100000/64)
#define C_CHUNKS 250                  // edge chunks (scatter/hist blocks)
#define CHUNK 6400                    // edges per chunk; 250*6400 = 1,600,000
#define M_CNT (NB * C_CHUNKS)         // 390,750 bucket-major counters
#define SCANA_BLOCKS ((M_CNT + 1023) / 1024)   // 382

typedef __attribute__((ext_vector_type(8))) short short8;
typedef __attribute__((ext_vector_type(4))) float f32x4;

#define LDS_PITCH 136

__device__ __forceinline__ unsigned short f2bf(float x) {
    unsigned u = __float_as_uint(x);
    return (unsigned short)((u + 0x7FFFu + ((u >> 16) & 1u)) >> 16);  // RNE
}
__device__ __forceinline__ float bf2f_u(unsigned short b) {
    return __uint_as_float((unsigned)b << 16);
}

// ---------------------------------------------------------------------------
// K1: per-chunk bucket histogram -> cnt[b*C_CHUNKS + c]; block C_CHUNKS
// additionally computes wa1 = W@a1, wa2 = W@a2 (fused, saves a launch).
// ---------------------------------------------------------------------------
__global__ __launch_bounds__(1024) void k_hist(
    const int* __restrict__ ei, int* __restrict__ cnt,
    const float* __restrict__ W, const float* __restrict__ a1,
    const float* __restrict__ a2, float* __restrict__ wa1, float* __restrict__ wa2)
{
    __shared__ int hl[NB];
    const int c = blockIdx.x;
    if (c == C_CHUNKS) {                 // fused k_wa
        const int k = threadIdx.x;
        if (k < IN_F) {
            float s1 = 0.f, s2 = 0.f;
            #pragma unroll 8
            for (int f = 0; f < OUT_F; f++) {
                const float w = W[k * OUT_F + f];
                s1 += w * a1[f];
                s2 += w * a2[f];
            }
            wa1[k] = s1;
            wa2[k] = s2;
        }
        return;
    }
    for (int i = threadIdx.x; i < NB; i += 1024) hl[i] = 0;
    __syncthreads();
    const int e0 = c * CHUNK;
    for (int i = threadIdx.x; i < CHUNK; i += 1024)
        atomicAdd(&hl[ei[e0 + i] >> 6], 1);
    __syncthreads();
    for (int b = threadIdx.x; b < NB; b += 1024)
        cnt[b * C_CHUNKS + c] = hl[b];
}

// ---------------------------------------------------------------------------
// K2: Wh = h @ W via bf16 MFMA; f1/f2 fused in fp32. Wh stored bf16.
// ---------------------------------------------------------------------------
__global__ __launch_bounds__(256) void k_gemm(
    const float* __restrict__ h, const float* __restrict__ W,
    const float* __restrict__ wa1, const float* __restrict__ wa2,
    unsigned short* __restrict__ Whb, float* __restrict__ f1, float* __restrict__ f2)
{
    __shared__ unsigned short Wt[OUT_F * LDS_PITCH];
    __shared__ unsigned short Al[16 * LDS_PITCH];

    const int tid  = threadIdx.x;
    const int lane = tid & 63;
    const int wav  = tid >> 6;
    const int quad = lane >> 4;
    const int nl   = lane & 15;

    for (int i = tid; i < IN_F * OUT_F; i += 256) {
        const int k = i >> 6, f = i & 63;
        Wt[f * LDS_PITCH + k] = f2bf(W[i]);
    }
    __syncthreads();

    short8 bfrag[4];
    #pragma unroll
    for (int ch = 0; ch < 4; ch++)
        bfrag[ch] = *(const short8*)&Wt[(wav * 16 + nl) * LDS_PITCH + ch * 32 + quad * 8];

    const int srow = tid >> 4;
    const int sc   = tid & 15;
    float w1r[8], w2r[8];
    #pragma unroll
    for (int j = 0; j < 8; j++) { w1r[j] = wa1[sc * 8 + j]; w2r[j] = wa2[sc * 8 + j]; }

    const int ntiles = N_NODES / 16;
    for (int tile = blockIdx.x; tile < ntiles; tile += gridDim.x) {
        const int base = tile * 16;
        __syncthreads();

        const float4 v0 = *(const float4*)&h[(base + srow) * IN_F + sc * 8];
        const float4 v1 = *(const float4*)&h[(base + srow) * IN_F + sc * 8 + 4];
        float p1 = v0.x * w1r[0] + v0.y * w1r[1] + v0.z * w1r[2] + v0.w * w1r[3]
                 + v1.x * w1r[4] + v1.y * w1r[5] + v1.z * w1r[6] + v1.w * w1r[7];
        float p2 = v0.x * w2r[0] + v0.y * w2r[1] + v0.z * w2r[2] + v0.w * w2r[3]
                 + v1.x * w2r[4] + v1.y * w2r[5] + v1.z * w2r[6] + v1.w * w2r[7];
        #pragma unroll
        for (int m = 8; m >= 1; m >>= 1) {
            p1 += __shfl_xor(p1, m, 64);
            p2 += __shfl_xor(p2, m, 64);
        }
        if (sc == 0) { f1[base + srow] = p1; f2[base + srow] = p2; }

        uint4 packed;
        packed.x = (unsigned)f2bf(v0.x) | ((unsigned)f2bf(v0.y) << 16);
        packed.y = (unsigned)f2bf(v0.z) | ((unsigned)f2bf(v0.w) << 16);
        packed.z = (unsigned)f2bf(v1.x) | ((unsigned)f2bf(v1.y) << 16);
        packed.w = (unsigned)f2bf(v1.z) | ((unsigned)f2bf(v1.w) << 16);
        *(uint4*)&Al[srow * LDS_PITCH + sc * 8] = packed;

        __syncthreads();

        f32x4 acc = {0.f, 0.f, 0.f, 0.f};
        #pragma unroll
        for (int ch = 0; ch < 4; ch++) {
            const short8 afrag = *(const short8*)&Al[nl * LDS_PITCH + ch * 32 + quad * 8];
            acc = __builtin_amdgcn_mfma_f32_16x16x32_bf16(afrag, bfrag[ch], acc, 0, 0, 0);
        }

        const int col = wav * 16 + nl;
        #pragma unroll
        for (int r = 0; r < 4; r++)
            Whb[(base + quad * 4 + r) * OUT_F + col] = f2bf(acc[r]);
    }
}

// ---------------------------------------------------------------------------
// K3a: per-1024-chunk totals of cnt
// ---------------------------------------------------------------------------
__global__ __launch_bounds__(256) void k_scanA(const int* __restrict__ cnt,
                                               int* __restrict__ bsum)
{
    __shared__ int sd[256];
    const int t = threadIdx.x;
    const int i0 = blockIdx.x * 1024 + t * 4;
    int s = 0;
    #pragma unroll
    for (int k = 0; k < 4; k++) {
        const int i = i0 + k;
        s += (i < M_CNT) ? cnt[i] : 0;
    }
    sd[t] = s; __syncthreads();
    for (int off = 128; off >= 1; off >>= 1) {
        if (t < off) sd[t] += sd[t + off];
        __syncthreads();
    }
    if (t == 0) bsum[blockIdx.x] = sd[0];
}

// ---------------------------------------------------------------------------
// K3b: in-place exclusive scan of cnt (each block reduces its bsum prefix)
// ---------------------------------------------------------------------------
__global__ __launch_bounds__(256) void k_scanC(int* __restrict__ cnt,
                                               const int* __restrict__ bsum)
{
    __shared__ int red[256];
    __shared__ int ts[256];
    const int t = threadIdx.x;

    int pv = 0;
    for (int i = t; i < (int)blockIdx.x; i += 256) pv += bsum[i];
    red[t] = pv; __syncthreads();
    for (int off = 128; off >= 1; off >>= 1) {
        if (t < off) red[t] += red[t + off];
        __syncthreads();
    }
    const int bpref = red[0];

    const int i0 = blockIdx.x * 1024 + t * 4;
    int v[4]; int s = 0;
    #pragma unroll
    for (int k = 0; k < 4; k++) {
        const int i = i0 + k;
        v[k] = (i < M_CNT) ? cnt[i] : 0;
        s += v[k];
    }
    ts[t] = s; __syncthreads();
    for (int off = 1; off < 256; off <<= 1) {
        const int x = (t >= off) ? ts[t - off] : 0;
        __syncthreads();
        ts[t] += x;
        __syncthreads();
    }
    int excl = ts[t] - s + bpref;
    #pragma unroll
    for (int k = 0; k < 4; k++) {
        const int i = i0 + k;
        if (i < M_CNT) cnt[i] = excl;
        excl += v[k];
    }
}

// ---------------------------------------------------------------------------
// K4: binned scatter (LDS cursors only). pair = {(rlocal<<17)|col, eexp}
// ---------------------------------------------------------------------------
__global__ __launch_bounds__(1024) void k_scatter(
    const int* __restrict__ ei,
    const float* __restrict__ f1,
    const float* __restrict__ f2,
    const int* __restrict__ cnt,
    uint2* __restrict__ pairs)
{
    __shared__ int cur[NB];
    const int c = blockIdx.x;
    for (int b = threadIdx.x; b < NB; b += 1024)
        cur[b] = cnt[b * C_CHUNKS + c];
    __syncthreads();

    const int e0 = c * CHUNK;
    for (int i = threadIdx.x; i < CHUNK; i += 1024) {
        const int r  = ei[e0 + i];
        const int cl = ei[N_EDGES + e0 + i];
        float x = f1[r] + f2[cl];
        x = (x >= 0.f) ? x : 0.2f * x;
        const float ee = __expf(x);
        const int pos = atomicAdd(&cur[r >> 6], 1);
        pairs[pos] = make_uint2(((unsigned)(r & 63) << 17) | (unsigned)cl,
                                __float_as_uint(ee));
    }
}

// ---------------------------------------------------------------------------
// K5: per-bucket streaming row-sort: pairs -> pairs2 (row-grouped) + rowptr
// ---------------------------------------------------------------------------
__global__ __launch_bounds__(256) void k_sort(
    const int* __restrict__ cnt,
    const uint2* __restrict__ pairs,
    uint2* __restrict__ pairs2,
    int* __restrict__ rowptr)
{
    __shared__ int cnt64[64];
    __shared__ int cur64[64];

    const int b   = blockIdx.x;
    const int tid = threadIdx.x;
    const int start = cnt[b * C_CHUNKS];
    const int end   = (b == NB - 1) ? N_EDGES : cnt[(b + 1) * C_CHUNKS];

    if (tid < 64) cnt64[tid] = 0;
    __syncthreads();

    for (int i = start + tid; i < end; i += 256)
        atomicAdd(&cnt64[pairs[i].x >> 17], 1);
    __syncthreads();

    if (tid < 64) {
        const int v = cnt64[tid];
        int s = v;
        #pragma unroll
        for (int off = 1; off < 64; off <<= 1) {
            const int x = __shfl_up(s, off, 64);
            if (tid >= off) s += x;
        }
        cur64[tid] = s - v;
        const int g = b * 64 + tid;
        if (g < N_NODES) rowptr[g] = start + s - v;
    }
    __syncthreads();

    for (int i = start + tid; i < end; i += 256) {
        const uint2 p = pairs[i];
        const int pos = atomicAdd(&cur64[p.x >> 17], 1);
        pairs2[start + pos] = p;
    }
    if (b == 0 && tid == 0) rowptr[N_NODES] = N_EDGES;
}

// ---------------------------------------------------------------------------
// K6: wave-per-node aggregation — round-8 proven explicit-batch structure
// (separate load window / use window, no masking), bf16 Wh gathers.
// ---------------------------------------------------------------------------
__global__ __launch_bounds__(256) void k_agg(
    const int* __restrict__ rowptr,
    const uint2* __restrict__ pairs2,
    const unsigned short* __restrict__ Whb,
    float* __restrict__ out)
{
    const int wid  = (blockIdx.x * 256 + threadIdx.x) >> 6;
    const int lane = threadIdx.x & 63;
    if (wid >= N_NODES) return;

    const int start = rowptr[wid];
    const int end   = rowptr[wid + 1];

    float acc = 0.f, s = 0.f;
    int j = start;

    for (; j + 8 <= end; j += 8) {
        uint2 p[8];
        #pragma unroll
        for (int k = 0; k < 8; k++) p[k] = pairs2[j + k];
        float wh[8];
        #pragma unroll
        for (int k = 0; k < 8; k++)
            wh[k] = bf2f_u(Whb[(((int)(p[k].x & 0x1FFFFu)) << 6) + lane]);
        #pragma unroll
        for (int k = 0; k < 8; k++) {
            const float ee = __uint_as_float(p[k].y);
            acc += ee * wh[k];
            s   += ee;
        }
    }
    for (; j + 4 <= end; j += 4) {
        uint2 p[4];
        #pragma unroll
        for (int k = 0; k < 4; k++) p[k] = pairs2[j + k];
        float wh[4];
        #pragma unroll
        for (int k = 0; k < 4; k++)
            wh[k] = bf2f_u(Whb[(((int)(p[k].x & 0x1FFFFu)) << 6) + lane]);
        #pragma unroll
        for (int k = 0; k < 4; k++) {
            const float ee = __uint_as_float(p[k].y);
            acc += ee * wh[k];
            s   += ee;
        }
    }
    for (; j < end; j++) {
        const uint2 p = pairs2[j];
        const float ee = __uint_as_float(p.y);
        acc += ee * bf2f_u(Whb[(((int)(p.x & 0x1FFFFu)) << 6) + lane]);
        s   += ee;
    }

    const float r = acc / (s + 1e-10f);
    out[wid * OUT_F + lane] = (r > 0.f) ? r : expm1f(r);
}

extern "C" void kernel_launch(void* const* d_in, const int* in_sizes, int n_in,
                              void* d_out, int out_size, void* d_ws, size_t ws_size,
                              hipStream_t stream) {
    const float* h  = (const float*)d_in[0];
    const float* W  = (const float*)d_in[1];
    const float* a1 = (const float*)d_in[2];
    const float* a2 = (const float*)d_in[3];
    const int* ei   = (const int*)d_in[4];
    float* out      = (float*)d_out;

    float* ws = (float*)d_ws;
    unsigned short* Whb = (unsigned short*)ws;        // 6.4M ushort = 3.2M f
    float* f1     = ws + 3200000;                     // 100,000
    float* f2     = f1 + N_NODES;                     // 100,000
    float* wa1    = f2 + N_NODES;                     // 128
    float* wa2    = wa1 + 128;                        // 128
    int*   cnt    = (int*)(wa2 + 128);                // 390,750
    int*   bsum   = cnt + M_CNT;                      // 384
    int*   rowptr = bsum + 384;                       // 100,002
    int*   pad    = rowptr + 100002;
    if ((size_t)(pad - (int*)ws) & 1) pad++;          // 8B align
    uint2* pairs  = (uint2*)pad;                      // 1.6M x 8B
    uint2* pairs2 = pairs + N_EDGES;                  // 1.6M x 8B

    k_hist   <<<C_CHUNKS + 1, 1024, 0, stream>>>(ei, cnt, W, a1, a2, wa1, wa2);
    k_scanA  <<<SCANA_BLOCKS, 256, 0, stream>>>(cnt, bsum);
    k_scanC  <<<SCANA_BLOCKS, 256, 0, stream>>>(cnt, bsum);
    k_gemm   <<<1250, 256, 0, stream>>>(h, W, wa1, wa2, Whb, f1, f2);
    k_scatter<<<C_CHUNKS, 1024, 0, stream>>>(ei, f1, f2, cnt, pairs);
    k_sort   <<<NB, 256, 0, stream>>>(cnt, pairs, pairs2, rowptr);
    k_agg    <<<(N_NODES * 64 + 255) / 256, 256, 0, stream>>>(rowptr, pairs2, Whb, out);
}